// Round 17
// baseline (4322.266 us; speedup 1.0000x reference)
//
#include <hip/hip_runtime.h>
#include <hip/hip_bf16.h>

#define BB 4
#define MM 8192
#define SS1 2048
#define SS2 512

using ull = unsigned long long;
typedef float f32x2 __attribute__((ext_vector_type(2)));

// ---------------- packed f32 helpers (VOP3P, per-element IEEE-identical) ----------------
__device__ __forceinline__ f32x2 pk_add(f32x2 a, f32x2 b) {
  f32x2 r; asm("v_pk_add_f32 %0, %1, %2" : "=v"(r) : "v"(a), "v"(b)); return r;
}
__device__ __forceinline__ f32x2 pk_mul(f32x2 a, f32x2 b) {
  f32x2 r; asm("v_pk_mul_f32 %0, %1, %2" : "=v"(r) : "v"(a), "v"(b)); return r;
}

// ---------------- DPP helpers ----------
template <int CTRL>
__device__ __forceinline__ void dpp_max_step(ull& k) {
  unsigned lo = (unsigned)k, hi = (unsigned)(k >> 32);
  unsigned plo = (unsigned)__builtin_amdgcn_update_dpp(0, (int)lo, CTRL, 0xF, 0xF, true);
  unsigned phi = (unsigned)__builtin_amdgcn_update_dpp(0, (int)hi, CTRL, 0xF, 0xF, true);
  ull pk = ((ull)phi << 32) | plo;
  if (pk > k) k = pk;
}

// full-wave max, result in lane 63
__device__ __forceinline__ void wave_max_u64(ull& k) {
  dpp_max_step<0x111>(k);
  dpp_max_step<0x112>(k);
  dpp_max_step<0x114>(k);
  dpp_max_step<0x118>(k);
  dpp_max_step<0x142>(k);
  dpp_max_step<0x143>(k);
}

// 8-lane max (entries in lanes 0..7), result in lane 7
__device__ __forceinline__ void row8_max_u64(ull& k) {
  dpp_max_step<0x111>(k);
  dpp_max_step<0x112>(k);
  dpp_max_step<0x114>(k);
}

// ---------------- farthest point sampling core (8 waves, tree-argmax) ----------------
// Exact f32 numpy semantics (contract-off order; pk per-element IEEE-identical;
// a+(-c)==a-c bitwise). Keys (d2<<32)|~idx; ties -> lowest original index.
// R17: in-thread selection spine converted from a 16-deep sequential compare
// chain to a balanced tree (depth 4). Tie-break provably identical: leaves
// ordered by element index ascending; every merge keeps LEFT unless RIGHT is
// STRICTLY greater == ascending strict-> scan semantics.
template <int MP, int NSEL, int THREADS>
__device__ __forceinline__ void fps_core(const float* __restrict__ p,
                                         float* __restrict__ c_out,
                                         char* smem) {
  constexpr int E = MP / THREADS;
  constexpr int P = E / 2;
  constexpr int W = THREADS / 64;
  static_assert(W == 8, "row8 tail assumes exactly 8 waves");
  static_assert(MP % THREADS == 0 && (E % 2) == 0 && (P & (P - 1)) == 0, "geometry");
  float4* sp = (float4*)smem;                                   // 16*MP
  float* cbuf = (float*)(smem + sizeof(float4) * MP);           // 12*NSEL
  ull* kb = (ull*)(smem + sizeof(float4) * MP + sizeof(float) * NSEL * 3);  // 2*W*8
  int t = threadIdx.x;
  int lane = t & 63, wv = t >> 6;
  for (int i = t; i < MP; i += THREADS)
    sp[i] = make_float4(p[i * 3 + 0], p[i * 3 + 1], p[i * 3 + 2], 0.f);
  __syncthreads();
  f32x2 X[P], Y[P], Z[P], D[P];
  #pragma unroll
  for (int pp = 0; pp < P; ++pp) {
    float4 qa = sp[t + (2 * pp + 0) * THREADS];
    float4 qb = sp[t + (2 * pp + 1) * THREADS];
    X[pp] = (f32x2){qa.x, qb.x};
    Y[pp] = (f32x2){qa.y, qb.y};
    Z[pp] = (f32x2){qa.z, qb.z};
    D[pp] = (f32x2){INFINITY, INFINITY};
  }
  float4 c0 = sp[0];
  float cx = c0.x, cy = c0.y, cz = c0.z;
  if (t == 0) { cbuf[0] = cx; cbuf[1] = cy; cbuf[2] = cz; }
  int par = 0;
  for (int it = 1; it < NSEL; ++it) {
    float ncx = -cx, ncy = -cy, ncz = -cz;
    f32x2 NX = (f32x2){ncx, ncx}, NY = (f32x2){ncy, ncy}, NZ = (f32x2){ncz, ncz};
    float v4[P];
    int e4[P];
    #pragma unroll
    for (int pp = 0; pp < P; ++pp) {
      f32x2 dx = pk_add(X[pp], NX);
      f32x2 dy = pk_add(Y[pp], NY);
      f32x2 dz = pk_add(Z[pp], NZ);
      f32x2 sx = pk_mul(dx, dx);
      f32x2 sy = pk_mul(dy, dy);
      f32x2 s1 = pk_add(sx, sy);
      f32x2 sz = pk_mul(dz, dz);
      f32x2 nd = pk_add(s1, sz);
      float d0 = fminf(D[pp].x, nd.x);
      float d1 = fminf(D[pp].y, nd.y);
      D[pp].x = d0;
      D[pp].y = d1;
      bool gg = d1 > d0;  // strict: keep lower e on tie
      v4[pp] = gg ? d1 : d0;
      e4[pp] = gg ? 2 * pp + 1 : 2 * pp;
    }
    // balanced tree over P leaves (depth log2(P)); left kept unless right strictly greater
    #pragma unroll
    for (int s = 1; s < P; s <<= 1) {
      #pragma unroll
      for (int i = 0; i + s < P; i += 2 * s) {
        bool gg = v4[i + s] > v4[i];
        v4[i] = gg ? v4[i + s] : v4[i];
        e4[i] = gg ? e4[i + s] : e4[i];
      }
    }
    float bd = v4[0];
    int be = e4[0];
    int bidx = t + be * THREADS;  // idx monotone in e -> in-thread ties exact
    ull k = ((ull)__float_as_uint(bd) << 32) | (unsigned)(~bidx);
    wave_max_u64(k);
    if (lane == 63) kb[par * W + wv] = k;
    __syncthreads();
    ull v = 0;
    if (lane < W) v = kb[par * W + lane];
    row8_max_u64(v);
    unsigned glo = __builtin_amdgcn_readlane((unsigned)v, 7);
    int widx = (int)(~glo) & (MP - 1);
    float4 cw = sp[widx];  // uniform address -> LDS broadcast
    cx = cw.x; cy = cw.y; cz = cw.z;
    if (t == 0) {
      cbuf[it * 3 + 0] = cx;
      cbuf[it * 3 + 1] = cy;
      cbuf[it * 3 + 2] = cz;
    }
    par ^= 1;
  }
  __syncthreads();
  for (int i = t; i < NSEL * 3; i += THREADS) c_out[i] = cbuf[i];
}

// ---------------- single-wave FPS core (R7-verified structure, tree-argmax) ----------------
// One wave owns the whole batch: NO barriers, NO cross-wave reduce, NO kb.
// R17: 32-deep selection spine -> pair level + depth-4 tree (same tie-break
// proof as fps_core). Centers stored directly to global (no barrier drain).
template <int MP, int NSEL>
__device__ __forceinline__ void fps_core_1w(const float* __restrict__ p,
                                            float* __restrict__ c_out,
                                            char* smem) {
  constexpr int E = MP / 64;
  constexpr int H = E / 2;
  static_assert((E % 2) == 0 && (H & (H - 1)) == 0, "geometry");
  float4* sp = (float4*)smem;
  int lane = threadIdx.x & 63;
  for (int i = lane; i < MP; i += 64)
    sp[i] = make_float4(p[i * 3 + 0], p[i * 3 + 1], p[i * 3 + 2], 0.f);
  asm volatile("s_waitcnt lgkmcnt(0)" ::: "memory");  // same-wave staging visible
  float mx[E], my[E], mz[E], dd[E];
  #pragma unroll
  for (int e = 0; e < E; ++e) {
    float4 q = sp[lane + e * 64];
    mx[e] = q.x; my[e] = q.y; mz[e] = q.z;
    dd[e] = INFINITY;
  }
  float4 c0 = sp[0];
  float cx = c0.x, cy = c0.y, cz = c0.z;
  if (lane == 0) { c_out[0] = cx; c_out[1] = cy; c_out[2] = cz; }
  for (int it = 1; it < NSEL; ++it) {
    {
      #pragma clang fp contract(off)
      #pragma unroll
      for (int e = 0; e < E; ++e) {
        float dx = mx[e] - cx, dy = my[e] - cy, dz = mz[e] - cz;
        float nd = dx * dx;
        nd += dy * dy;
        nd += dz * dz;
        dd[e] = fminf(dd[e], nd);
      }
    }
    // pair level + balanced tree (depth log2(H)); strict > keeps lowest e on ties
    float vh[H];
    int eh[H];
    #pragma unroll
    for (int i = 0; i < H; ++i) {
      bool gg = dd[2 * i + 1] > dd[2 * i];
      vh[i] = gg ? dd[2 * i + 1] : dd[2 * i];
      eh[i] = gg ? 2 * i + 1 : 2 * i;
    }
    #pragma unroll
    for (int s = 1; s < H; s <<= 1) {
      #pragma unroll
      for (int i = 0; i + s < H; i += 2 * s) {
        bool gg = vh[i + s] > vh[i];
        vh[i] = gg ? vh[i + s] : vh[i];
        eh[i] = gg ? eh[i + s] : eh[i];
      }
    }
    int bidx = lane + eh[0] * 64;
    ull k = ((ull)__float_as_uint(vh[0]) << 32) | (unsigned)(~bidx);
    wave_max_u64(k);  // lane63 = wave (= batch) max
    unsigned glo = __builtin_amdgcn_readlane((unsigned)k, 63);
    int widx = (int)(~glo) & (MP - 1);
    float4 cw = sp[widx];  // uniform address -> LDS broadcast
    cx = cw.x; cy = cw.y; cz = cw.z;
    if (lane == 0) {  // fire-and-forget stores; no barrier ever drains them
      c_out[it * 3 + 0] = cx;
      c_out[it * 3 + 1] = cy;
      c_out[it * 3 + 2] = cz;
    }
  }
}

// ---------------- wave-local ball query: 64 nearest with d2 <= R2, ties by lower index ----------------
// R12/R13-verified. Pure wave-local; per-wave 8KB LDS buffer.
template <int MP>
__device__ __forceinline__ int nbr_wave(const float* __restrict__ p,
                                        float cx, float cy, float cz,
                                        float R2, ull* bw) {
  constexpr int CAP = 1024;
  int lane = threadIdx.x & 63;
  int cnt = 0;
  {
    #pragma clang fp contract(off)
    for (int i0 = 0; i0 < MP; i0 += 64) {
      int i = i0 + lane;
      float dx = p[i * 3 + 0] - cx;
      float dy = p[i * 3 + 1] - cy;
      float dz = p[i * 3 + 2] - cz;
      float d2 = dx * dx;
      d2 += dy * dy;
      d2 += dz * dz;
      bool in = (d2 <= R2);
      ull mask = __ballot(in);
      if (in) {
        int off = __popcll(mask & ((1ull << lane) - 1ull));
        int pos = cnt + off;
        if (pos < CAP)
          bw[pos] = ((ull)__float_as_uint(d2) << 32) | (unsigned)i;
      }
      cnt += __popcll(mask);
    }
  }
  if (cnt > CAP) cnt = CAP;
  asm volatile("s_waitcnt lgkmcnt(0)" ::: "memory");  // same-wave LDS RAW
  int out = -1;
  if (cnt <= 64) {
    if (lane < cnt) out = (int)(unsigned)bw[lane];
  } else {
    for (int r = 0; r < 64; ++r) {
      ull mk = ~0ull;
      int mj = -1;
      for (int j = lane; j < cnt; j += 64) {
        ull v = bw[j];
        if (v < mk) { mk = v; mj = j; }
      }
      ull kc = ~mk;
      wave_max_u64(kc);
      ull g = ~__shfl(kc, 63, 64);
      if (mk == g && mj >= 0) bw[mj] = ~0ull;  // unique keys -> exactly one owner
      asm volatile("s_waitcnt lgkmcnt(0)" ::: "memory");
      if (lane == r) out = (int)(unsigned)g;
    }
  }
  return out;
}

// ======================================================================
// K_A: fps1 (blocks 0..3) U local MLP (blocks 4..)
// ======================================================================
__global__ __launch_bounds__(512) void k_fps1_local(
    const float* __restrict__ pos, float* __restrict__ c1,
    const float* __restrict__ w0, const float* __restrict__ b0,
    const float* __restrict__ w1, const float* __restrict__ b1,
    const float* __restrict__ w2, const float* __restrict__ b2,
    float* __restrict__ out) {
  __shared__ __align__(16) char smem[16 * MM + 12 * SS1 + 128];  // 155,776 B
  if (blockIdx.x < BB) {
    int b = blockIdx.x;
    fps_core<MM, SS1, 512>(pos + (size_t)b * MM * 3, c1 + (size_t)b * SS1 * 3, smem);
  } else {
    float* p  = (float*)smem;           // [8][3]
    float* h0 = (float*)smem + 32;      // [8][64]
    float* h1 = (float*)smem + 32 + 512;// [8][64]
    int t = threadIdx.x;
    size_t pid0 = (size_t)(blockIdx.x - BB) * 8;
    if (t < 24) {
      int pp = t / 3, j = t % 3;
      p[pp * 3 + j] = pos[(pid0 + pp) * 3 + j];
    }
    __syncthreads();
    {
      int pp = t >> 6, c = t & 63;
      float acc = b0[c];
      #pragma unroll
      for (int j = 0; j < 3; ++j) acc += p[pp * 3 + j] * w0[j * 64 + c];
      h0[pp * 64 + c] = tanhf(acc);
    }
    __syncthreads();
    {
      int pp = t >> 6, c = t & 63;
      float acc = b1[c];
      #pragma unroll
      for (int j = 0; j < 64; ++j) acc += h0[pp * 64 + j] * w1[j * 64 + c];
      h1[pp * 64 + c] = tanhf(acc);
    }
    __syncthreads();
    #pragma unroll
    for (int r = 0; r < 2; ++r) {
      int o = t + 512 * r;
      int pp = o >> 7, c = o & 127;
      float acc = b2[c];
      #pragma unroll
      for (int j = 0; j < 64; ++j) acc += h1[pp * 64 + j] * w2[j * 128 + c];
      out[(pid0 + pp) * 128 + c] = tanhf(acc);
    }
  }
}

// standalone fps1 (fallback path: local must run LAST when scratch aliases d_out)
__global__ __launch_bounds__(512, 1) void fps1_kernel(const float* __restrict__ pts,
                                                      float* __restrict__ cen) {
  __shared__ __align__(16) char smem[16 * MM + 12 * SS1 + 128];
  fps_core<MM, SS1, 512>(pts + (size_t)blockIdx.x * MM * 3,
                         cen + (size_t)blockIdx.x * SS1 * 3, smem);
}

// standalone local MLP (fallback path), 8 pts per 512-thread block
__global__ __launch_bounds__(512) void local_mlp_kernel(
    const float* __restrict__ pos,
    const float* __restrict__ w0, const float* __restrict__ b0,
    const float* __restrict__ w1, const float* __restrict__ b1,
    const float* __restrict__ w2, const float* __restrict__ b2,
    float* __restrict__ out) {
  __shared__ float p[8][3];
  __shared__ float h0[8][64];
  __shared__ float h1[8][64];
  int t = threadIdx.x;
  size_t pid0 = (size_t)blockIdx.x * 8;
  if (t < 24) {
    int pp = t / 3, j = t % 3;
    p[pp][j] = pos[(pid0 + pp) * 3 + j];
  }
  __syncthreads();
  {
    int pp = t >> 6, c = t & 63;
    float acc = b0[c];
    #pragma unroll
    for (int j = 0; j < 3; ++j) acc += p[pp][j] * w0[j * 64 + c];
    h0[pp][c] = tanhf(acc);
  }
  __syncthreads();
  {
    int pp = t >> 6, c = t & 63;
    float acc = b1[c];
    #pragma unroll
    for (int j = 0; j < 64; ++j) acc += h0[pp][j] * w1[j * 64 + c];
    h1[pp][c] = tanhf(acc);
  }
  __syncthreads();
  #pragma unroll
  for (int r = 0; r < 2; ++r) {
    int o = t + 512 * r;
    int pp = o >> 7, c = o & 127;
    float acc = b2[c];
    #pragma unroll
    for (int j = 0; j < 64; ++j) acc += h1[pp][j] * w2[j * 128 + c];
    out[(pid0 + pp) * 128 + c] = tanhf(acc);
  }
}

// ======================================================================
// K_B: fps2 single-wave (blocks 0..3, EXCLUSIVE CUs via 131KB LDS) U
// group1-with-embedded-nbr1 (blocks 4..1027, g1w1 LDS-staged).
// ======================================================================
__global__ __launch_bounds__(512) void k_fps2_g1(
    const float* __restrict__ pos, const float* __restrict__ x,
    const float* __restrict__ c1, float* __restrict__ c2,
    const float* __restrict__ g1w0, const float* __restrict__ g1b0,
    const float* __restrict__ g1w1, const float* __restrict__ g1b1,
    float* __restrict__ h1out) {
  __shared__ __align__(16) char smem[131264];
  int t = threadIdx.x;
  if (blockIdx.x < BB) {
    if (t >= 64) return;  // single-wave path: NO barriers below
    int b = blockIdx.x;
    fps_core_1w<SS1, SS2>(c1 + (size_t)b * SS1 * 3, c2 + (size_t)b * SS2 * 3, smem);
    return;
  }
  int g = blockIdx.x - BB;  // 0..1023, one 8-center task per block
  int lane = t & 63, wv = t >> 6;
  ull* bw = (ull*)smem + (size_t)wv * 1024;       // [8][1024] ull = 64KB
  int* nbs = (int*)(smem + 65536);                // [8][64] int
  float* cbl = (float*)(smem + 67584);            // [8][3]
  int tt = t & 255, half = t >> 8;
  {  // wave wv: neighbor query for center g*8+wv
    int cs = g * 8 + wv;
    int b = cs >> 11;
    const float* cp = c1 + (size_t)cs * 3;
    float cx = cp[0], cy = cp[1], cz = cp[2];
    int nout = nbr_wave<MM>(pos + (size_t)b * MM * 3, cx, cy, cz, 0.04f, bw);
    nbs[wv * 64 + lane] = nout;
    if (lane == 0) { cbl[wv * 3 + 0] = cx; cbl[wv * 3 + 1] = cy; cbl[wv * 3 + 2] = cz; }
  }
  __syncthreads();
  // stage g1w1 (64x128 f32 = 32KB) into the now-dead bw region
  {
    float4* wd = (float4*)smem;
    const float4* wsrc = (const float4*)g1w1;
    for (int i = t; i < 2048; i += 512) wd[i] = wsrc[i];
  }
  __syncthreads();
  const float* wlds = (const float*)smem;
  // dual-half group1: 4 rounds x 2 centers (R12/R13-verified math)
  for (int r = 0; r < 4; ++r) {
    int c_loc = 2 * r + half;
    int cs2 = g * 8 + c_loc;
    int bb = cs2 >> 11;
    float* feats = (float*)(smem + 67712 + half * 24576);  // [64][12]
    float* hbuf  = feats + 768;                            // [64][68]
    float* Mred  = hbuf + 4352;                            // [8][128]
    const int* nbp = nbs + c_loc * 64;
    const float* ccp = cbl + c_loc * 3;
    if (tt < 64) {
      int n = nbp[tt];
      int ni = ((unsigned)n < (unsigned)MM) ? n : 0;
      const float* pp = pos + ((size_t)bb * MM + ni) * 3;
      const float* xx = x + ((size_t)bb * MM + ni) * 3;
      float p0 = pp[0], p1 = pp[1], p2 = pp[2];
      float* fr = feats + tt * 12;
      fr[0] = p0; fr[1] = p1; fr[2] = p2;
      fr[3] = xx[0]; fr[4] = xx[1]; fr[5] = xx[2];
      fr[6] = p0 - ccp[0]; fr[7] = p1 - ccp[1]; fr[8] = p2 - ccp[2];
    }
    __syncthreads();
    {
      int k = tt >> 2, q4 = tt & 3;
      float acc[16];
      #pragma unroll
      for (int i = 0; i < 16; ++i) acc[i] = g1b0[q4 * 16 + i];
      #pragma unroll
      for (int j = 0; j < 9; ++j) {
        float f = feats[k * 12 + j];
        const float4* wr = (const float4*)(g1w0 + j * 64 + q4 * 16);
        #pragma unroll
        for (int i = 0; i < 4; ++i) {
          float4 wvv = wr[i];
          acc[4 * i + 0] += f * wvv.x;
          acc[4 * i + 1] += f * wvv.y;
          acc[4 * i + 2] += f * wvv.z;
          acc[4 * i + 3] += f * wvv.w;
        }
      }
      #pragma unroll
      for (int i = 0; i < 16; ++i) hbuf[k * 68 + q4 * 16 + i] = tanhf(acc[i]);
    }
    __syncthreads();
    {
      int kt = tt >> 5, ct = tt & 31;
      float acc[8][4];
      #pragma unroll
      for (int a = 0; a < 8; ++a)
        #pragma unroll
        for (int ci = 0; ci < 4; ++ci) acc[a][ci] = 0.f;
      const float* wbase = wlds + ct * 4;  // LDS-staged weights
      #pragma unroll 2
      for (int j = 0; j < 64; j += 2) {
        float2 fv[8];
        #pragma unroll
        for (int kk = 0; kk < 8; ++kk)
          fv[kk] = *(const float2*)&hbuf[(kt * 8 + kk) * 68 + j];
        float wja[4], wjb[4];
        *(float4*)&wja[0] = *(const float4*)(wbase + (size_t)j * 128);
        *(float4*)&wjb[0] = *(const float4*)(wbase + (size_t)(j + 1) * 128);
        #pragma unroll
        for (int kk = 0; kk < 8; ++kk)
          #pragma unroll
          for (int ci = 0; ci < 4; ++ci) {
            acc[kk][ci] += fv[kk].x * wja[ci];
            acc[kk][ci] += fv[kk].y * wjb[ci];
          }
      }
      float m[4];
      #pragma unroll
      for (int ci = 0; ci < 4; ++ci) m[ci] = -INFINITY;
      #pragma unroll
      for (int kk = 0; kk < 8; ++kk) {
        if (nbp[kt * 8 + kk] >= 0) {
          #pragma unroll
          for (int ci = 0; ci < 4; ++ci) m[ci] = fmaxf(m[ci], acc[kk][ci]);
        }
      }
      #pragma unroll
      for (int ci = 0; ci < 4; ++ci) Mred[kt * 128 + ct * 4 + ci] = m[ci];
    }
    __syncthreads();
    if (tt < 128) {
      float mxv = Mred[tt];
      #pragma unroll
      for (int r8 = 1; r8 < 8; ++r8) mxv = fmaxf(mxv, Mred[r8 * 128 + tt]);
      h1out[(size_t)cs2 * 128 + tt] = tanhf(mxv + g1b1[tt]);
    }
    __syncthreads();
  }
}

// ======================================================================
// K_C: group2-with-embedded-nbr2: 256 blocks x 8 centers.
// g2w0 rows 0..127 (64KB) staged into the dead bw region; layer2 unroll 4.
// ======================================================================
__global__ __launch_bounds__(512) void k_g2(
    const float* __restrict__ c1, const float* __restrict__ c2,
    const float* __restrict__ h1,
    const float* __restrict__ g2w0, const float* __restrict__ g2b0,
    const float* __restrict__ g2w1, const float* __restrict__ g2b1,
    float* __restrict__ h2out) {
  __shared__ __align__(16) char smem[151744];
  int t = threadIdx.x;
  int g = blockIdx.x;  // 0..255, one 8-center task per block
  int lane = t & 63, wv = t >> 6;
  ull* bw = (ull*)smem + (size_t)wv * 1024;
  int* nbs = (int*)(smem + 65536);
  float* cbl = (float*)(smem + 67584);
  int tt = t & 255, half = t >> 8;
  {
    int cs = g * 8 + wv;
    int b = cs >> 9;
    const float* cp = c2 + (size_t)cs * 3;
    float cx = cp[0], cy = cp[1], cz = cp[2];
    int nout = nbr_wave<SS1>(c1 + (size_t)b * SS1 * 3, cx, cy, cz, 0.16f, bw);
    nbs[wv * 64 + lane] = nout;
    if (lane == 0) { cbl[wv * 3 + 0] = cx; cbl[wv * 3 + 1] = cy; cbl[wv * 3 + 2] = cz; }
  }
  __syncthreads();
  // stage g2w0 rows 0..127 (128x128 f32 = 64KB) into the dead bw region
  {
    float4* wd = (float4*)smem;
    const float4* wsrc = (const float4*)g2w0;
    for (int i = t; i < 4096; i += 512) wd[i] = wsrc[i];
  }
  __syncthreads();
  const float* w0lds = (const float*)smem;
  for (int r = 0; r < 4; ++r) {
    int c_loc = 2 * r + half;
    int cs2 = g * 8 + c_loc;
    int bb = cs2 >> 9;
    float* fb   = (float*)(smem + 67712 + half * 41984);  // [64][132]
    float* Mred = fb + 64 * 132;                          // [8][256]
    const int* nbp = nbs + c_loc * 64;
    const float* ccp = cbl + c_loc * 3;
    {
      int k = tt >> 2, q4 = tt & 3;
      int n = nbp[k];
      int ni = ((unsigned)n < (unsigned)SS1) ? n : 0;
      const float* hrow = h1 + ((size_t)bb * SS1 + ni) * 128;
      #pragma unroll
      for (int i = 0; i < 32; ++i) fb[k * 132 + q4 * 32 + i] = hrow[q4 * 32 + i];
      if (q4 == 0) {
        const float* pr = c1 + ((size_t)bb * SS1 + ni) * 3;
        fb[k * 132 + 128] = pr[0] - ccp[0];
        fb[k * 132 + 129] = pr[1] - ccp[1];
        fb[k * 132 + 130] = pr[2] - ccp[2];
      }
    }
    __syncthreads();
    float acc1[32];
    {
      int k = tt >> 2, q4 = tt & 3;
      #pragma unroll
      for (int i = 0; i < 32; ++i) acc1[i] = g2b0[q4 * 32 + i];
      #pragma unroll 2
      for (int j = 0; j < 128; ++j) {  // rows 0..127 from LDS
        float f = fb[k * 132 + j];
        const float4* wr = (const float4*)(w0lds + (size_t)j * 128 + q4 * 32);
        #pragma unroll
        for (int i = 0; i < 8; ++i) {
          float4 wvv = wr[i];
          acc1[4 * i + 0] += f * wvv.x;
          acc1[4 * i + 1] += f * wvv.y;
          acc1[4 * i + 2] += f * wvv.z;
          acc1[4 * i + 3] += f * wvv.w;
        }
      }
      #pragma unroll
      for (int j = 128; j < 131; ++j) {  // last 3 rows from global
        float f = fb[k * 132 + j];
        const float4* wr = (const float4*)(g2w0 + (size_t)j * 128 + q4 * 32);
        #pragma unroll
        for (int i = 0; i < 8; ++i) {
          float4 wvv = wr[i];
          acc1[4 * i + 0] += f * wvv.x;
          acc1[4 * i + 1] += f * wvv.y;
          acc1[4 * i + 2] += f * wvv.z;
          acc1[4 * i + 3] += f * wvv.w;
        }
      }
    }
    __syncthreads();
    {
      int k = tt >> 2, q4 = tt & 3;
      #pragma unroll
      for (int i = 0; i < 32; ++i) fb[k * 132 + q4 * 32 + i] = tanhf(acc1[i]);
    }
    __syncthreads();
    {
      int kt = tt >> 5, ct = tt & 31;
      float acc[8][8];
      #pragma unroll
      for (int a = 0; a < 8; ++a)
        #pragma unroll
        for (int ci = 0; ci < 8; ++ci) acc[a][ci] = 0.f;
      const float* wbase = g2w1 + ct * 8;
      #pragma unroll 4
      for (int j = 0; j < 128; j += 2) {
        float2 fv[8];
        #pragma unroll
        for (int kk = 0; kk < 8; ++kk)
          fv[kk] = *(const float2*)&fb[(kt * 8 + kk) * 132 + j];
        float wja[8], wjb[8];
        const float4* wp0 = (const float4*)(wbase + (size_t)j * 256);
        const float4* wp1 = (const float4*)(wbase + (size_t)(j + 1) * 256);
        *(float4*)&wja[0] = wp0[0];
        *(float4*)&wja[4] = wp0[1];
        *(float4*)&wjb[0] = wp1[0];
        *(float4*)&wjb[4] = wp1[1];
        #pragma unroll
        for (int kk = 0; kk < 8; ++kk)
          #pragma unroll
          for (int ci = 0; ci < 8; ++ci) {
            acc[kk][ci] += fv[kk].x * wja[ci];
            acc[kk][ci] += fv[kk].y * wjb[ci];
          }
      }
      float m[8];
      #pragma unroll
      for (int ci = 0; ci < 8; ++ci) m[ci] = -INFINITY;
      #pragma unroll
      for (int kk = 0; kk < 8; ++kk) {
        if (nbp[kt * 8 + kk] >= 0) {
          #pragma unroll
          for (int ci = 0; ci < 8; ++ci) m[ci] = fmaxf(m[ci], acc[kk][ci]);
        }
      }
      #pragma unroll
      for (int ci = 0; ci < 8; ++ci) Mred[kt * 256 + ct * 8 + ci] = m[ci];
    }
    __syncthreads();
    {
      float mxv = Mred[tt];
      #pragma unroll
      for (int r8 = 1; r8 < 8; ++r8) mxv = fmaxf(mxv, Mred[r8 * 256 + tt]);
      h2out[(size_t)cs2 * 256 + tt] = tanhf(mxv + g2b1[tt]);
    }
    __syncthreads();
  }
}

// ---------------- global max over centers ----------------
__global__ __launch_bounds__(256) void gmax_kernel(const float* __restrict__ h2,
                                                   float* __restrict__ out) {
  int b = blockIdx.x, c = threadIdx.x;
  float mx = -INFINITY;
  for (int s = 0; s < SS2; ++s)
    mx = fmaxf(mx, h2[((size_t)b * SS2 + s) * 256 + c]);
  out[(size_t)BB * MM * 128 + b * 256 + c] = mx;
}

extern "C" void kernel_launch(void* const* d_in, const int* in_sizes, int n_in,
                              void* d_out, int out_size, void* d_ws, size_t ws_size,
                              hipStream_t stream) {
  const float* x    = (const float*)d_in[0];
  const float* pos  = (const float*)d_in[1];
  const float* lw0  = (const float*)d_in[2];
  const float* lb0  = (const float*)d_in[3];
  const float* lw1  = (const float*)d_in[4];
  const float* lb1  = (const float*)d_in[5];
  const float* lw2  = (const float*)d_in[6];
  const float* lb2  = (const float*)d_in[7];
  const float* g1w0 = (const float*)d_in[8];
  const float* g1b0 = (const float*)d_in[9];
  const float* g1w1 = (const float*)d_in[10];
  const float* g1b1 = (const float*)d_in[11];
  const float* g2w0 = (const float*)d_in[12];
  const float* g2b0 = (const float*)d_in[13];
  const float* g2w1 = (const float*)d_in[14];
  const float* g2b1 = (const float*)d_in[15];
  float* out = (float*)d_out;

  // Scratch (6.41 MB: nbr arrays eliminated -- embedded in group kernels).
  // Prefer d_ws; fall back to the local-output region of d_out (16.8 MB):
  // then local_mlp must run LAST and fps1 standalone FIRST.
  const size_t NEED = 6414336;
  bool has_ws = (ws_size >= NEED);
  char* sc = has_ws ? (char*)d_ws : (char*)d_out;
  float* h1 = (float*)(sc + 0);        // 4*2048*128 f32 = 4,194,304 B
  float* h2 = (float*)(sc + 4194304);  // 4*512*256 f32  = 2,097,152 B
  float* c1 = (float*)(sc + 6291456);  // 4*2048*3 f32   =    98,304 B
  float* c2 = (float*)(sc + 6389760);  // 4*512*3 f32    =    24,576 B

  if (has_ws) {
    k_fps1_local<<<BB + BB * MM / 8, 512, 0, stream>>>(
        pos, c1, lw0, lb0, lw1, lb1, lw2, lb2, out);
  } else {
    fps1_kernel<<<BB, 512, 0, stream>>>(pos, c1);
  }
  k_fps2_g1<<<BB + BB * SS1 / 8, 512, 0, stream>>>(
      pos, x, c1, c2, g1w0, g1b0, g1w1, g1b1, h1);
  k_g2<<<BB * SS2 / 8, 512, 0, stream>>>(
      c1, c2, h1, g2w0, g2b0, g2w1, g2b1, h2);
  gmax_kernel<<<BB, 256, 0, stream>>>(h2, out);
  if (!has_ws) {
    local_mlp_kernel<<<BB * MM / 8, 512, 0, stream>>>(pos, lw0, lb0, lw1, lb1, lw2, lb2, out);
  }
}

// Round 18
// 3091.648 us; speedup vs baseline: 1.3980x; 1.3980x over previous
//
#include <hip/hip_runtime.h>
#include <hip/hip_bf16.h>

#define BB 4
#define MM 8192
#define SS1 2048
#define SS2 512

using ull = unsigned long long;
typedef float f32x2 __attribute__((ext_vector_type(2)));

// ---------------- packed f32 helpers (VOP3P, per-element IEEE-identical) ----------------
__device__ __forceinline__ f32x2 pk_add(f32x2 a, f32x2 b) {
  f32x2 r; asm("v_pk_add_f32 %0, %1, %2" : "=v"(r) : "v"(a), "v"(b)); return r;
}
__device__ __forceinline__ f32x2 pk_mul(f32x2 a, f32x2 b) {
  f32x2 r; asm("v_pk_mul_f32 %0, %1, %2" : "=v"(r) : "v"(a), "v"(b)); return r;
}

// ---------------- DPP helpers ----------
template <int CTRL>
__device__ __forceinline__ void dpp_max_step(ull& k) {
  unsigned lo = (unsigned)k, hi = (unsigned)(k >> 32);
  unsigned plo = (unsigned)__builtin_amdgcn_update_dpp(0, (int)lo, CTRL, 0xF, 0xF, true);
  unsigned phi = (unsigned)__builtin_amdgcn_update_dpp(0, (int)hi, CTRL, 0xF, 0xF, true);
  ull pk = ((ull)phi << 32) | plo;
  if (pk > k) k = pk;
}

// full-wave max, result in lane 63
__device__ __forceinline__ void wave_max_u64(ull& k) {
  dpp_max_step<0x111>(k);
  dpp_max_step<0x112>(k);
  dpp_max_step<0x114>(k);
  dpp_max_step<0x118>(k);
  dpp_max_step<0x142>(k);
  dpp_max_step<0x143>(k);
}

// 8-lane max (entries in lanes 0..7), result in lane 7
__device__ __forceinline__ void row8_max_u64(ull& k) {
  dpp_max_step<0x111>(k);
  dpp_max_step<0x112>(k);
  dpp_max_step<0x114>(k);
}

// ---------------- farthest point sampling core (8 waves, R10-proven floor) ----------------
// Exact f32 numpy semantics (contract-off order; pk per-element IEEE-identical;
// a+(-c)==a-c bitwise). Keys (d2<<32)|~idx; ties -> lowest original index.
// R17 post-mortem: the sequential bd/be compare spine is FULLY HIDDEN under
// the independent pk-FMA stream (tree-argmax variant regressed +31% -- it
// serialized selection after the math and added pressure). Do not touch.
template <int MP, int NSEL, int THREADS>
__device__ __forceinline__ void fps_core(const float* __restrict__ p,
                                         float* __restrict__ c_out,
                                         char* smem) {
  constexpr int E = MP / THREADS;
  constexpr int P = E / 2;
  constexpr int W = THREADS / 64;
  static_assert(W == 8, "row8 tail assumes exactly 8 waves");
  static_assert(MP % THREADS == 0 && (E % 2) == 0, "geometry");
  float4* sp = (float4*)smem;                                   // 16*MP
  float* cbuf = (float*)(smem + sizeof(float4) * MP);           // 12*NSEL
  ull* kb = (ull*)(smem + sizeof(float4) * MP + sizeof(float) * NSEL * 3);  // 2*W*8
  int t = threadIdx.x;
  int lane = t & 63, wv = t >> 6;
  for (int i = t; i < MP; i += THREADS)
    sp[i] = make_float4(p[i * 3 + 0], p[i * 3 + 1], p[i * 3 + 2], 0.f);
  __syncthreads();
  f32x2 X[P], Y[P], Z[P], D[P];
  #pragma unroll
  for (int pp = 0; pp < P; ++pp) {
    float4 qa = sp[t + (2 * pp + 0) * THREADS];
    float4 qb = sp[t + (2 * pp + 1) * THREADS];
    X[pp] = (f32x2){qa.x, qb.x};
    Y[pp] = (f32x2){qa.y, qb.y};
    Z[pp] = (f32x2){qa.z, qb.z};
    D[pp] = (f32x2){INFINITY, INFINITY};
  }
  float4 c0 = sp[0];
  float cx = c0.x, cy = c0.y, cz = c0.z;
  if (t == 0) { cbuf[0] = cx; cbuf[1] = cy; cbuf[2] = cz; }
  int par = 0;
  for (int it = 1; it < NSEL; ++it) {
    float bd = -1.0f;
    int be = 0;
    float ncx = -cx, ncy = -cy, ncz = -cz;
    f32x2 NX = (f32x2){ncx, ncx}, NY = (f32x2){ncy, ncy}, NZ = (f32x2){ncz, ncz};
    #pragma unroll
    for (int pp = 0; pp < P; ++pp) {
      f32x2 dx = pk_add(X[pp], NX);
      f32x2 dy = pk_add(Y[pp], NY);
      f32x2 dz = pk_add(Z[pp], NZ);
      f32x2 sx = pk_mul(dx, dx);
      f32x2 sy = pk_mul(dy, dy);
      f32x2 s1 = pk_add(sx, sy);
      f32x2 sz = pk_mul(dz, dz);
      f32x2 nd = pk_add(s1, sz);
      float d0 = fminf(D[pp].x, nd.x);
      float d1 = fminf(D[pp].y, nd.y);
      D[pp].x = d0;
      D[pp].y = d1;
      if (d0 > bd) { bd = d0; be = 2 * pp; }
      if (d1 > bd) { bd = d1; be = 2 * pp + 1; }
    }
    int bidx = t + be * THREADS;  // idx monotone in e -> in-thread ties exact
    ull k = ((ull)__float_as_uint(bd) << 32) | (unsigned)(~bidx);
    wave_max_u64(k);
    if (lane == 63) kb[par * W + wv] = k;
    __syncthreads();
    ull v = 0;
    if (lane < W) v = kb[par * W + lane];
    row8_max_u64(v);
    unsigned glo = __builtin_amdgcn_readlane((unsigned)v, 7);
    int widx = (int)(~glo) & (MP - 1);
    float4 cw = sp[widx];  // uniform address -> LDS broadcast
    cx = cw.x; cy = cw.y; cz = cw.z;
    if (t == 0) {
      cbuf[it * 3 + 0] = cx;
      cbuf[it * 3 + 1] = cy;
      cbuf[it * 3 + 2] = cz;
    }
    par ^= 1;
  }
  __syncthreads();
  for (int i = t; i < NSEL * 3; i += THREADS) c_out[i] = cbuf[i];
}

// ---------------- wave-local ball query: 64 nearest with d2 <= R2, ties by lower index ----------------
// R12/R13-verified. Pure wave-local; per-wave 8KB LDS buffer.
template <int MP>
__device__ __forceinline__ int nbr_wave(const float* __restrict__ p,
                                        float cx, float cy, float cz,
                                        float R2, ull* bw) {
  constexpr int CAP = 1024;
  int lane = threadIdx.x & 63;
  int cnt = 0;
  {
    #pragma clang fp contract(off)
    for (int i0 = 0; i0 < MP; i0 += 64) {
      int i = i0 + lane;
      float dx = p[i * 3 + 0] - cx;
      float dy = p[i * 3 + 1] - cy;
      float dz = p[i * 3 + 2] - cz;
      float d2 = dx * dx;
      d2 += dy * dy;
      d2 += dz * dz;
      bool in = (d2 <= R2);
      ull mask = __ballot(in);
      if (in) {
        int off = __popcll(mask & ((1ull << lane) - 1ull));
        int pos = cnt + off;
        if (pos < CAP)
          bw[pos] = ((ull)__float_as_uint(d2) << 32) | (unsigned)i;
      }
      cnt += __popcll(mask);
    }
  }
  if (cnt > CAP) cnt = CAP;
  asm volatile("s_waitcnt lgkmcnt(0)" ::: "memory");  // same-wave LDS RAW
  int out = -1;
  if (cnt <= 64) {
    if (lane < cnt) out = (int)(unsigned)bw[lane];
  } else {
    for (int r = 0; r < 64; ++r) {
      ull mk = ~0ull;
      int mj = -1;
      for (int j = lane; j < cnt; j += 64) {
        ull v = bw[j];
        if (v < mk) { mk = v; mj = j; }
      }
      ull kc = ~mk;
      wave_max_u64(kc);
      ull g = ~__shfl(kc, 63, 64);
      if (mk == g && mj >= 0) bw[mj] = ~0ull;  // unique keys -> exactly one owner
      asm volatile("s_waitcnt lgkmcnt(0)" ::: "memory");
      if (lane == r) out = (int)(unsigned)g;
    }
  }
  return out;
}

// ======================================================================
// K_A: fps1 (blocks 0..3) U local MLP (blocks 4..) -- R10 verbatim, 2040us
// ======================================================================
__global__ __launch_bounds__(512) void k_fps1_local(
    const float* __restrict__ pos, float* __restrict__ c1,
    const float* __restrict__ w0, const float* __restrict__ b0,
    const float* __restrict__ w1, const float* __restrict__ b1,
    const float* __restrict__ w2, const float* __restrict__ b2,
    float* __restrict__ out) {
  __shared__ __align__(16) char smem[16 * MM + 12 * SS1 + 128];  // 155,776 B
  if (blockIdx.x < BB) {
    int b = blockIdx.x;
    fps_core<MM, SS1, 512>(pos + (size_t)b * MM * 3, c1 + (size_t)b * SS1 * 3, smem);
  } else {
    float* p  = (float*)smem;           // [8][3]
    float* h0 = (float*)smem + 32;      // [8][64]
    float* h1 = (float*)smem + 32 + 512;// [8][64]
    int t = threadIdx.x;
    size_t pid0 = (size_t)(blockIdx.x - BB) * 8;
    if (t < 24) {
      int pp = t / 3, j = t % 3;
      p[pp * 3 + j] = pos[(pid0 + pp) * 3 + j];
    }
    __syncthreads();
    {
      int pp = t >> 6, c = t & 63;
      float acc = b0[c];
      #pragma unroll
      for (int j = 0; j < 3; ++j) acc += p[pp * 3 + j] * w0[j * 64 + c];
      h0[pp * 64 + c] = tanhf(acc);
    }
    __syncthreads();
    {
      int pp = t >> 6, c = t & 63;
      float acc = b1[c];
      #pragma unroll
      for (int j = 0; j < 64; ++j) acc += h0[pp * 64 + j] * w1[j * 64 + c];
      h1[pp * 64 + c] = tanhf(acc);
    }
    __syncthreads();
    #pragma unroll
    for (int r = 0; r < 2; ++r) {
      int o = t + 512 * r;
      int pp = o >> 7, c = o & 127;
      float acc = b2[c];
      #pragma unroll
      for (int j = 0; j < 64; ++j) acc += h1[pp * 64 + j] * w2[j * 128 + c];
      out[(pid0 + pp) * 128 + c] = tanhf(acc);
    }
  }
}

// standalone fps1 (fallback path: local must run LAST when scratch aliases d_out)
__global__ __launch_bounds__(512, 1) void fps1_kernel(const float* __restrict__ pts,
                                                      float* __restrict__ cen) {
  __shared__ __align__(16) char smem[16 * MM + 12 * SS1 + 128];
  fps_core<MM, SS1, 512>(pts + (size_t)blockIdx.x * MM * 3,
                         cen + (size_t)blockIdx.x * SS1 * 3, smem);
}

// standalone local MLP (fallback path), 8 pts per 512-thread block
__global__ __launch_bounds__(512) void local_mlp_kernel(
    const float* __restrict__ pos,
    const float* __restrict__ w0, const float* __restrict__ b0,
    const float* __restrict__ w1, const float* __restrict__ b1,
    const float* __restrict__ w2, const float* __restrict__ b2,
    float* __restrict__ out) {
  __shared__ float p[8][3];
  __shared__ float h0[8][64];
  __shared__ float h1[8][64];
  int t = threadIdx.x;
  size_t pid0 = (size_t)blockIdx.x * 8;
  if (t < 24) {
    int pp = t / 3, j = t % 3;
    p[pp][j] = pos[(pid0 + pp) * 3 + j];
  }
  __syncthreads();
  {
    int pp = t >> 6, c = t & 63;
    float acc = b0[c];
    #pragma unroll
    for (int j = 0; j < 3; ++j) acc += p[pp][j] * w0[j * 64 + c];
    h0[pp][c] = tanhf(acc);
  }
  __syncthreads();
  {
    int pp = t >> 6, c = t & 63;
    float acc = b1[c];
    #pragma unroll
    for (int j = 0; j < 64; ++j) acc += h0[pp][j] * w1[j * 64 + c];
    h1[pp][c] = tanhf(acc);
  }
  __syncthreads();
  #pragma unroll
  for (int r = 0; r < 2; ++r) {
    int o = t + 512 * r;
    int pp = o >> 7, c = o & 127;
    float acc = b2[c];
    #pragma unroll
    for (int j = 0; j < 64; ++j) acc += h1[pp][j] * w2[j * 128 + c];
    out[(pid0 + pp) * 128 + c] = tanhf(acc);
  }
}

// ======================================================================
// K_B: fps2 8-wave (blocks 0..3) U group1-with-embedded-nbr1 (blocks 4..1027).
// 131KB LDS -> 1 block/CU: fps2 gets EXCLUSIVE CUs. g1w1 (32KB) staged into
// LDS after the nbr phase (bw region dead then): layer2 weight reads become
// ds_read_b128 instead of ~300cy L2 round-trips (R15's -736us win).
// ======================================================================
__global__ __launch_bounds__(512) void k_fps2_g1(
    const float* __restrict__ pos, const float* __restrict__ x,
    const float* __restrict__ c1, float* __restrict__ c2,
    const float* __restrict__ g1w0, const float* __restrict__ g1b0,
    const float* __restrict__ g1w1, const float* __restrict__ g1b1,
    float* __restrict__ h1out) {
  __shared__ __align__(16) char smem[131264];
  int t = threadIdx.x;
  if (blockIdx.x < BB) {
    int b = blockIdx.x;
    fps_core<SS1, SS2, 512>(c1 + (size_t)b * SS1 * 3, c2 + (size_t)b * SS2 * 3, smem);
    return;
  }
  int g = blockIdx.x - BB;  // 0..1023, one 8-center task per block
  int lane = t & 63, wv = t >> 6;
  ull* bw = (ull*)smem + (size_t)wv * 1024;       // [8][1024] ull = 64KB
  int* nbs = (int*)(smem + 65536);                // [8][64] int
  float* cbl = (float*)(smem + 67584);            // [8][3]
  int tt = t & 255, half = t >> 8;
  {  // wave wv: neighbor query for center g*8+wv
    int cs = g * 8 + wv;
    int b = cs >> 11;
    const float* cp = c1 + (size_t)cs * 3;
    float cx = cp[0], cy = cp[1], cz = cp[2];
    int nout = nbr_wave<MM>(pos + (size_t)b * MM * 3, cx, cy, cz, 0.04f, bw);
    nbs[wv * 64 + lane] = nout;
    if (lane == 0) { cbl[wv * 3 + 0] = cx; cbl[wv * 3 + 1] = cy; cbl[wv * 3 + 2] = cz; }
  }
  __syncthreads();
  // stage g1w1 (64x128 f32 = 32KB) into the now-dead bw region
  {
    float4* wd = (float4*)smem;
    const float4* wsrc = (const float4*)g1w1;
    for (int i = t; i < 2048; i += 512) wd[i] = wsrc[i];
  }
  __syncthreads();
  const float* wlds = (const float*)smem;
  // dual-half group1: 4 rounds x 2 centers (R12/R13-verified math)
  for (int r = 0; r < 4; ++r) {
    int c_loc = 2 * r + half;
    int cs2 = g * 8 + c_loc;
    int bb = cs2 >> 11;
    float* feats = (float*)(smem + 67712 + half * 24576);  // [64][12]
    float* hbuf  = feats + 768;                            // [64][68]
    float* Mred  = hbuf + 4352;                            // [8][128]
    const int* nbp = nbs + c_loc * 64;
    const float* ccp = cbl + c_loc * 3;
    if (tt < 64) {
      int n = nbp[tt];
      int ni = ((unsigned)n < (unsigned)MM) ? n : 0;
      const float* pp = pos + ((size_t)bb * MM + ni) * 3;
      const float* xx = x + ((size_t)bb * MM + ni) * 3;
      float p0 = pp[0], p1 = pp[1], p2 = pp[2];
      float* fr = feats + tt * 12;
      fr[0] = p0; fr[1] = p1; fr[2] = p2;
      fr[3] = xx[0]; fr[4] = xx[1]; fr[5] = xx[2];
      fr[6] = p0 - ccp[0]; fr[7] = p1 - ccp[1]; fr[8] = p2 - ccp[2];
    }
    __syncthreads();
    {
      int k = tt >> 2, q4 = tt & 3;
      float acc[16];
      #pragma unroll
      for (int i = 0; i < 16; ++i) acc[i] = g1b0[q4 * 16 + i];
      #pragma unroll
      for (int j = 0; j < 9; ++j) {
        float f = feats[k * 12 + j];
        const float4* wr = (const float4*)(g1w0 + j * 64 + q4 * 16);
        #pragma unroll
        for (int i = 0; i < 4; ++i) {
          float4 wvv = wr[i];
          acc[4 * i + 0] += f * wvv.x;
          acc[4 * i + 1] += f * wvv.y;
          acc[4 * i + 2] += f * wvv.z;
          acc[4 * i + 3] += f * wvv.w;
        }
      }
      #pragma unroll
      for (int i = 0; i < 16; ++i) hbuf[k * 68 + q4 * 16 + i] = tanhf(acc[i]);
    }
    __syncthreads();
    {
      int kt = tt >> 5, ct = tt & 31;
      float acc[8][4];
      #pragma unroll
      for (int a = 0; a < 8; ++a)
        #pragma unroll
        for (int ci = 0; ci < 4; ++ci) acc[a][ci] = 0.f;
      const float* wbase = wlds + ct * 4;  // LDS-staged weights
      #pragma unroll 2
      for (int j = 0; j < 64; j += 2) {
        float2 fv[8];
        #pragma unroll
        for (int kk = 0; kk < 8; ++kk)
          fv[kk] = *(const float2*)&hbuf[(kt * 8 + kk) * 68 + j];
        float wja[4], wjb[4];
        *(float4*)&wja[0] = *(const float4*)(wbase + (size_t)j * 128);
        *(float4*)&wjb[0] = *(const float4*)(wbase + (size_t)(j + 1) * 128);
        #pragma unroll
        for (int kk = 0; kk < 8; ++kk)
          #pragma unroll
          for (int ci = 0; ci < 4; ++ci) {
            acc[kk][ci] += fv[kk].x * wja[ci];
            acc[kk][ci] += fv[kk].y * wjb[ci];
          }
      }
      float m[4];
      #pragma unroll
      for (int ci = 0; ci < 4; ++ci) m[ci] = -INFINITY;
      #pragma unroll
      for (int kk = 0; kk < 8; ++kk) {
        if (nbp[kt * 8 + kk] >= 0) {
          #pragma unroll
          for (int ci = 0; ci < 4; ++ci) m[ci] = fmaxf(m[ci], acc[kk][ci]);
        }
      }
      #pragma unroll
      for (int ci = 0; ci < 4; ++ci) Mred[kt * 128 + ct * 4 + ci] = m[ci];
    }
    __syncthreads();
    if (tt < 128) {
      float mxv = Mred[tt];
      #pragma unroll
      for (int r8 = 1; r8 < 8; ++r8) mxv = fmaxf(mxv, Mred[r8 * 128 + tt]);
      h1out[(size_t)cs2 * 128 + tt] = tanhf(mxv + g1b1[tt]);
    }
    __syncthreads();
  }
}

// ======================================================================
// K_C: group2-with-embedded-nbr2: 256 blocks x 8 centers.
// g2w0 rows 0..127 (64KB) staged into the dead bw region; layer2 unroll 4.
// ======================================================================
__global__ __launch_bounds__(512) void k_g2(
    const float* __restrict__ c1, const float* __restrict__ c2,
    const float* __restrict__ h1,
    const float* __restrict__ g2w0, const float* __restrict__ g2b0,
    const float* __restrict__ g2w1, const float* __restrict__ g2b1,
    float* __restrict__ h2out) {
  __shared__ __align__(16) char smem[151744];
  int t = threadIdx.x;
  int g = blockIdx.x;  // 0..255, one 8-center task per block
  int lane = t & 63, wv = t >> 6;
  ull* bw = (ull*)smem + (size_t)wv * 1024;
  int* nbs = (int*)(smem + 65536);
  float* cbl = (float*)(smem + 67584);
  int tt = t & 255, half = t >> 8;
  {
    int cs = g * 8 + wv;
    int b = cs >> 9;
    const float* cp = c2 + (size_t)cs * 3;
    float cx = cp[0], cy = cp[1], cz = cp[2];
    int nout = nbr_wave<SS1>(c1 + (size_t)b * SS1 * 3, cx, cy, cz, 0.16f, bw);
    nbs[wv * 64 + lane] = nout;
    if (lane == 0) { cbl[wv * 3 + 0] = cx; cbl[wv * 3 + 1] = cy; cbl[wv * 3 + 2] = cz; }
  }
  __syncthreads();
  // stage g2w0 rows 0..127 (128x128 f32 = 64KB) into the dead bw region
  {
    float4* wd = (float4*)smem;
    const float4* wsrc = (const float4*)g2w0;
    for (int i = t; i < 4096; i += 512) wd[i] = wsrc[i];
  }
  __syncthreads();
  const float* w0lds = (const float*)smem;
  for (int r = 0; r < 4; ++r) {
    int c_loc = 2 * r + half;
    int cs2 = g * 8 + c_loc;
    int bb = cs2 >> 9;
    float* fb   = (float*)(smem + 67712 + half * 41984);  // [64][132]
    float* Mred = fb + 64 * 132;                          // [8][256]
    const int* nbp = nbs + c_loc * 64;
    const float* ccp = cbl + c_loc * 3;
    {
      int k = tt >> 2, q4 = tt & 3;
      int n = nbp[k];
      int ni = ((unsigned)n < (unsigned)SS1) ? n : 0;
      const float* hrow = h1 + ((size_t)bb * SS1 + ni) * 128;
      #pragma unroll
      for (int i = 0; i < 32; ++i) fb[k * 132 + q4 * 32 + i] = hrow[q4 * 32 + i];
      if (q4 == 0) {
        const float* pr = c1 + ((size_t)bb * SS1 + ni) * 3;
        fb[k * 132 + 128] = pr[0] - ccp[0];
        fb[k * 132 + 129] = pr[1] - ccp[1];
        fb[k * 132 + 130] = pr[2] - ccp[2];
      }
    }
    __syncthreads();
    float acc1[32];
    {
      int k = tt >> 2, q4 = tt & 3;
      #pragma unroll
      for (int i = 0; i < 32; ++i) acc1[i] = g2b0[q4 * 32 + i];
      #pragma unroll 2
      for (int j = 0; j < 128; ++j) {  // rows 0..127 from LDS
        float f = fb[k * 132 + j];
        const float4* wr = (const float4*)(w0lds + (size_t)j * 128 + q4 * 32);
        #pragma unroll
        for (int i = 0; i < 8; ++i) {
          float4 wvv = wr[i];
          acc1[4 * i + 0] += f * wvv.x;
          acc1[4 * i + 1] += f * wvv.y;
          acc1[4 * i + 2] += f * wvv.z;
          acc1[4 * i + 3] += f * wvv.w;
        }
      }
      #pragma unroll
      for (int j = 128; j < 131; ++j) {  // last 3 rows from global
        float f = fb[k * 132 + j];
        const float4* wr = (const float4*)(g2w0 + (size_t)j * 128 + q4 * 32);
        #pragma unroll
        for (int i = 0; i < 8; ++i) {
          float4 wvv = wr[i];
          acc1[4 * i + 0] += f * wvv.x;
          acc1[4 * i + 1] += f * wvv.y;
          acc1[4 * i + 2] += f * wvv.z;
          acc1[4 * i + 3] += f * wvv.w;
        }
      }
    }
    __syncthreads();
    {
      int k = tt >> 2, q4 = tt & 3;
      #pragma unroll
      for (int i = 0; i < 32; ++i) fb[k * 132 + q4 * 32 + i] = tanhf(acc1[i]);
    }
    __syncthreads();
    {
      int kt = tt >> 5, ct = tt & 31;
      float acc[8][8];
      #pragma unroll
      for (int a = 0; a < 8; ++a)
        #pragma unroll
        for (int ci = 0; ci < 8; ++ci) acc[a][ci] = 0.f;
      const float* wbase = g2w1 + ct * 8;
      #pragma unroll 4
      for (int j = 0; j < 128; j += 2) {
        float2 fv[8];
        #pragma unroll
        for (int kk = 0; kk < 8; ++kk)
          fv[kk] = *(const float2*)&fb[(kt * 8 + kk) * 132 + j];
        float wja[8], wjb[8];
        const float4* wp0 = (const float4*)(wbase + (size_t)j * 256);
        const float4* wp1 = (const float4*)(wbase + (size_t)(j + 1) * 256);
        *(float4*)&wja[0] = wp0[0];
        *(float4*)&wja[4] = wp0[1];
        *(float4*)&wjb[0] = wp1[0];
        *(float4*)&wjb[4] = wp1[1];
        #pragma unroll
        for (int kk = 0; kk < 8; ++kk)
          #pragma unroll
          for (int ci = 0; ci < 8; ++ci) {
            acc[kk][ci] += fv[kk].x * wja[ci];
            acc[kk][ci] += fv[kk].y * wjb[ci];
          }
      }
      float m[8];
      #pragma unroll
      for (int ci = 0; ci < 8; ++ci) m[ci] = -INFINITY;
      #pragma unroll
      for (int kk = 0; kk < 8; ++kk) {
        if (nbp[kt * 8 + kk] >= 0) {
          #pragma unroll
          for (int ci = 0; ci < 8; ++ci) m[ci] = fmaxf(m[ci], acc[kk][ci]);
        }
      }
      #pragma unroll
      for (int ci = 0; ci < 8; ++ci) Mred[kt * 256 + ct * 8 + ci] = m[ci];
    }
    __syncthreads();
    {
      float mxv = Mred[tt];
      #pragma unroll
      for (int r8 = 1; r8 < 8; ++r8) mxv = fmaxf(mxv, Mred[r8 * 256 + tt]);
      h2out[(size_t)cs2 * 256 + tt] = tanhf(mxv + g2b1[tt]);
    }
    __syncthreads();
  }
}

// ---------------- global max over centers ----------------
__global__ __launch_bounds__(256) void gmax_kernel(const float* __restrict__ h2,
                                                   float* __restrict__ out) {
  int b = blockIdx.x, c = threadIdx.x;
  float mx = -INFINITY;
  for (int s = 0; s < SS2; ++s)
    mx = fmaxf(mx, h2[((size_t)b * SS2 + s) * 256 + c]);
  out[(size_t)BB * MM * 128 + b * 256 + c] = mx;
}

extern "C" void kernel_launch(void* const* d_in, const int* in_sizes, int n_in,
                              void* d_out, int out_size, void* d_ws, size_t ws_size,
                              hipStream_t stream) {
  const float* x    = (const float*)d_in[0];
  const float* pos  = (const float*)d_in[1];
  const float* lw0  = (const float*)d_in[2];
  const float* lb0  = (const float*)d_in[3];
  const float* lw1  = (const float*)d_in[4];
  const float* lb1  = (const float*)d_in[5];
  const float* lw2  = (const float*)d_in[6];
  const float* lb2  = (const float*)d_in[7];
  const float* g1w0 = (const float*)d_in[8];
  const float* g1b0 = (const float*)d_in[9];
  const float* g1w1 = (const float*)d_in[10];
  const float* g1b1 = (const float*)d_in[11];
  const float* g2w0 = (const float*)d_in[12];
  const float* g2b0 = (const float*)d_in[13];
  const float* g2w1 = (const float*)d_in[14];
  const float* g2b1 = (const float*)d_in[15];
  float* out = (float*)d_out;

  // Scratch (6.41 MB: nbr arrays eliminated -- embedded in group kernels).
  // Prefer d_ws; fall back to the local-output region of d_out (16.8 MB):
  // then local_mlp must run LAST and fps1 standalone FIRST.
  const size_t NEED = 6414336;
  bool has_ws = (ws_size >= NEED);
  char* sc = has_ws ? (char*)d_ws : (char*)d_out;
  float* h1 = (float*)(sc + 0);        // 4*2048*128 f32 = 4,194,304 B
  float* h2 = (float*)(sc + 4194304);  // 4*512*256 f32  = 2,097,152 B
  float* c1 = (float*)(sc + 6291456);  // 4*2048*3 f32   =    98,304 B
  float* c2 = (float*)(sc + 6389760);  // 4*512*3 f32    =    24,576 B

  if (has_ws) {
    k_fps1_local<<<BB + BB * MM / 8, 512, 0, stream>>>(
        pos, c1, lw0, lb0, lw1, lb1, lw2, lb2, out);
  } else {
    fps1_kernel<<<BB, 512, 0, stream>>>(pos, c1);
  }
  k_fps2_g1<<<BB + BB * SS1 / 8, 512, 0, stream>>>(
      pos, x, c1, c2, g1w0, g1b0, g1w1, g1b1, h1);
  k_g2<<<BB * SS2 / 8, 512, 0, stream>>>(
      c1, c2, h1, g2w0, g2b0, g2w1, g2b1, h2);
  gmax_kernel<<<BB, 256, 0, stream>>>(h2, out);
  if (!has_ws) {
    local_mlp_kernel<<<BB * MM / 8, 512, 0, stream>>>(pos, lw0, lb0, lw1, lb1, lw2, lb2, out);
  }
}

// Round 19
// 2945.845 us; speedup vs baseline: 1.4672x; 1.0495x over previous
//
#include <hip/hip_runtime.h>
#include <hip/hip_bf16.h>

#define BB 4
#define MM 8192
#define SS1 2048
#define SS2 512

using ull = unsigned long long;
typedef float f32x2 __attribute__((ext_vector_type(2)));

// ---------------- packed f32 helpers (VOP3P, per-element IEEE-identical) ----------------
__device__ __forceinline__ f32x2 pk_add(f32x2 a, f32x2 b) {
  f32x2 r; asm("v_pk_add_f32 %0, %1, %2" : "=v"(r) : "v"(a), "v"(b)); return r;
}
__device__ __forceinline__ f32x2 pk_mul(f32x2 a, f32x2 b) {
  f32x2 r; asm("v_pk_mul_f32 %0, %1, %2" : "=v"(r) : "v"(a), "v"(b)); return r;
}

// ---------------- DPP helpers ----------
template <int CTRL>
__device__ __forceinline__ void dpp_max_step(ull& k) {
  unsigned lo = (unsigned)k, hi = (unsigned)(k >> 32);
  unsigned plo = (unsigned)__builtin_amdgcn_update_dpp(0, (int)lo, CTRL, 0xF, 0xF, true);
  unsigned phi = (unsigned)__builtin_amdgcn_update_dpp(0, (int)hi, CTRL, 0xF, 0xF, true);
  ull pk = ((ull)phi << 32) | plo;
  if (pk > k) k = pk;
}

// full-wave max, result in lane 63
__device__ __forceinline__ void wave_max_u64(ull& k) {
  dpp_max_step<0x111>(k);
  dpp_max_step<0x112>(k);
  dpp_max_step<0x114>(k);
  dpp_max_step<0x118>(k);
  dpp_max_step<0x142>(k);
  dpp_max_step<0x143>(k);
}

// 8-lane max (entries in lanes 0..7), result in lane 7
__device__ __forceinline__ void row8_max_u64(ull& k) {
  dpp_max_step<0x111>(k);
  dpp_max_step<0x112>(k);
  dpp_max_step<0x114>(k);
}

// ---------------- cross-lane bitonic primitives (u64 keys, exact) ----------------
// sort64<ASC>: full bitonic sort of one value per lane across the 64-lane wave.
// Standard network: block direction at stage k is ascending iff (lane&k)==0
// (times ASC); lower pair element keeps min iff its block is ascending.
template <bool ASC>
__device__ __forceinline__ void sort64(ull& v) {
  int lane = threadIdx.x & 63;
  #pragma unroll
  for (int k = 2; k <= 64; k <<= 1) {
    #pragma unroll
    for (int j = k >> 1; j >= 1; j >>= 1) {
      ull o = __shfl_xor(v, j, 64);
      bool up = (((lane & k) == 0) == ASC);
      bool lower = (lane & j) == 0;
      bool keepmin = (lower == up);
      v = keepmin ? (v < o ? v : o) : (v > o ? v : o);
    }
  }
}

// clean64: input bitonic across lanes -> ascending sorted (6 stages).
__device__ __forceinline__ void clean64(ull& v) {
  int lane = threadIdx.x & 63;
  #pragma unroll
  for (int j = 32; j >= 1; j >>= 1) {
    ull o = __shfl_xor(v, j, 64);
    bool lower = (lane & j) == 0;
    v = lower ? (v < o ? v : o) : (v > o ? v : o);
  }
}

// ---------------- farthest point sampling core (8 waves, R10-proven floor) ----------------
// Exact f32 numpy semantics (contract-off order; pk per-element IEEE-identical;
// a+(-c)==a-c bitwise). Keys (d2<<32)|~idx; ties -> lowest original index.
// R17 post-mortem: the sequential bd/be compare spine is FULLY HIDDEN under
// the independent pk-FMA stream (tree-argmax variant regressed +31%). Do not touch.
template <int MP, int NSEL, int THREADS>
__device__ __forceinline__ void fps_core(const float* __restrict__ p,
                                         float* __restrict__ c_out,
                                         char* smem) {
  constexpr int E = MP / THREADS;
  constexpr int P = E / 2;
  constexpr int W = THREADS / 64;
  static_assert(W == 8, "row8 tail assumes exactly 8 waves");
  static_assert(MP % THREADS == 0 && (E % 2) == 0, "geometry");
  float4* sp = (float4*)smem;                                   // 16*MP
  float* cbuf = (float*)(smem + sizeof(float4) * MP);           // 12*NSEL
  ull* kb = (ull*)(smem + sizeof(float4) * MP + sizeof(float) * NSEL * 3);  // 2*W*8
  int t = threadIdx.x;
  int lane = t & 63, wv = t >> 6;
  for (int i = t; i < MP; i += THREADS)
    sp[i] = make_float4(p[i * 3 + 0], p[i * 3 + 1], p[i * 3 + 2], 0.f);
  __syncthreads();
  f32x2 X[P], Y[P], Z[P], D[P];
  #pragma unroll
  for (int pp = 0; pp < P; ++pp) {
    float4 qa = sp[t + (2 * pp + 0) * THREADS];
    float4 qb = sp[t + (2 * pp + 1) * THREADS];
    X[pp] = (f32x2){qa.x, qb.x};
    Y[pp] = (f32x2){qa.y, qb.y};
    Z[pp] = (f32x2){qa.z, qb.z};
    D[pp] = (f32x2){INFINITY, INFINITY};
  }
  float4 c0 = sp[0];
  float cx = c0.x, cy = c0.y, cz = c0.z;
  if (t == 0) { cbuf[0] = cx; cbuf[1] = cy; cbuf[2] = cz; }
  int par = 0;
  for (int it = 1; it < NSEL; ++it) {
    float bd = -1.0f;
    int be = 0;
    float ncx = -cx, ncy = -cy, ncz = -cz;
    f32x2 NX = (f32x2){ncx, ncx}, NY = (f32x2){ncy, ncy}, NZ = (f32x2){ncz, ncz};
    #pragma unroll
    for (int pp = 0; pp < P; ++pp) {
      f32x2 dx = pk_add(X[pp], NX);
      f32x2 dy = pk_add(Y[pp], NY);
      f32x2 dz = pk_add(Z[pp], NZ);
      f32x2 sx = pk_mul(dx, dx);
      f32x2 sy = pk_mul(dy, dy);
      f32x2 s1 = pk_add(sx, sy);
      f32x2 sz = pk_mul(dz, dz);
      f32x2 nd = pk_add(s1, sz);
      float d0 = fminf(D[pp].x, nd.x);
      float d1 = fminf(D[pp].y, nd.y);
      D[pp].x = d0;
      D[pp].y = d1;
      if (d0 > bd) { bd = d0; be = 2 * pp; }
      if (d1 > bd) { bd = d1; be = 2 * pp + 1; }
    }
    int bidx = t + be * THREADS;  // idx monotone in e -> in-thread ties exact
    ull k = ((ull)__float_as_uint(bd) << 32) | (unsigned)(~bidx);
    wave_max_u64(k);
    if (lane == 63) kb[par * W + wv] = k;
    __syncthreads();
    ull v = 0;
    if (lane < W) v = kb[par * W + lane];
    row8_max_u64(v);
    unsigned glo = __builtin_amdgcn_readlane((unsigned)v, 7);
    int widx = (int)(~glo) & (MP - 1);
    float4 cw = sp[widx];  // uniform address -> LDS broadcast
    cx = cw.x; cy = cw.y; cz = cw.z;
    if (t == 0) {
      cbuf[it * 3 + 0] = cx;
      cbuf[it * 3 + 1] = cy;
      cbuf[it * 3 + 2] = cz;
    }
    par ^= 1;
  }
  __syncthreads();
  for (int i = t; i < NSEL * 3; i += THREADS) c_out[i] = cbuf[i];
}

// ---------------- wave-local ball query: 64 nearest with d2 <= R2, ties by lower index ----------------
// R19: top-64 selection rebuilt as a bitonic tournament (downstream is a
// masked MAX-pool -> only the exact SET matters; the cnt<=64 path always
// exploited this). Old path: 64 sequential rounds x ~300cy (6-step dependent
// 64-bit DPP reduce each) ~= 6.7us/center. New: B=ceil(cnt/64) block-sorts
// (21 shfl_xor stages) + (B-1) merge-splits (elementwise min of ascending vs
// descending sorted + 6-stage clean) ~= 3.4us at cnt~274. Keys (d2<<32)|idx
// are UNIQUE -> comparison network is exact; u64 compares only.
template <int MP>
__device__ __forceinline__ int nbr_wave(const float* __restrict__ p,
                                        float cx, float cy, float cz,
                                        float R2, ull* bw) {
  constexpr int CAP = 1024;
  int lane = threadIdx.x & 63;
  int cnt = 0;
  {
    #pragma clang fp contract(off)
    for (int i0 = 0; i0 < MP; i0 += 64) {
      int i = i0 + lane;
      float dx = p[i * 3 + 0] - cx;
      float dy = p[i * 3 + 1] - cy;
      float dz = p[i * 3 + 2] - cz;
      float d2 = dx * dx;
      d2 += dy * dy;
      d2 += dz * dz;
      bool in = (d2 <= R2);
      ull mask = __ballot(in);
      if (in) {
        int off = __popcll(mask & ((1ull << lane) - 1ull));
        int pos = cnt + off;
        if (pos < CAP)
          bw[pos] = ((ull)__float_as_uint(d2) << 32) | (unsigned)i;
      }
      cnt += __popcll(mask);
    }
  }
  if (cnt > CAP) cnt = CAP;
  asm volatile("s_waitcnt lgkmcnt(0)" ::: "memory");  // same-wave LDS RAW
  int out = -1;
  if (cnt <= 64) {
    if (lane < cnt) out = (int)(unsigned)bw[lane];
  } else {
    int B = (cnt + 63) >> 6;  // <= 16 (B*64 <= CAP)
    // pad last block with max keys (cnt>64 -> the 64 smallest are all real)
    for (int j = lane; j < B * 64; j += 64)
      if (j >= cnt) bw[j] = ~0ull;
    asm volatile("s_waitcnt lgkmcnt(0)" ::: "memory");
    ull a = bw[lane];
    sort64<true>(a);  // ascending across lanes
    for (int blk = 1; blk < B; ++blk) {
      ull b = bw[blk * 64 + lane];
      sort64<false>(b);              // descending == reversed ascending
      ull lo = (b < a) ? b : a;      // merge-split: exact lower 64, bitonic
      clean64(lo);                   // -> ascending for the next merge
      a = lo;
    }
    out = (int)(unsigned)a;  // lane r holds the r-th smallest key's index
  }
  return out;
}

// ======================================================================
// K_A: fps1 (blocks 0..3) U local MLP (blocks 4..) -- R10 verbatim, 2040us
// ======================================================================
__global__ __launch_bounds__(512) void k_fps1_local(
    const float* __restrict__ pos, float* __restrict__ c1,
    const float* __restrict__ w0, const float* __restrict__ b0,
    const float* __restrict__ w1, const float* __restrict__ b1,
    const float* __restrict__ w2, const float* __restrict__ b2,
    float* __restrict__ out) {
  __shared__ __align__(16) char smem[16 * MM + 12 * SS1 + 128];  // 155,776 B
  if (blockIdx.x < BB) {
    int b = blockIdx.x;
    fps_core<MM, SS1, 512>(pos + (size_t)b * MM * 3, c1 + (size_t)b * SS1 * 3, smem);
  } else {
    float* p  = (float*)smem;           // [8][3]
    float* h0 = (float*)smem + 32;      // [8][64]
    float* h1 = (float*)smem + 32 + 512;// [8][64]
    int t = threadIdx.x;
    size_t pid0 = (size_t)(blockIdx.x - BB) * 8;
    if (t < 24) {
      int pp = t / 3, j = t % 3;
      p[pp * 3 + j] = pos[(pid0 + pp) * 3 + j];
    }
    __syncthreads();
    {
      int pp = t >> 6, c = t & 63;
      float acc = b0[c];
      #pragma unroll
      for (int j = 0; j < 3; ++j) acc += p[pp * 3 + j] * w0[j * 64 + c];
      h0[pp * 64 + c] = tanhf(acc);
    }
    __syncthreads();
    {
      int pp = t >> 6, c = t & 63;
      float acc = b1[c];
      #pragma unroll
      for (int j = 0; j < 64; ++j) acc += h0[pp * 64 + j] * w1[j * 64 + c];
      h1[pp * 64 + c] = tanhf(acc);
    }
    __syncthreads();
    #pragma unroll
    for (int r = 0; r < 2; ++r) {
      int o = t + 512 * r;
      int pp = o >> 7, c = o & 127;
      float acc = b2[c];
      #pragma unroll
      for (int j = 0; j < 64; ++j) acc += h1[pp * 64 + j] * w2[j * 128 + c];
      out[(pid0 + pp) * 128 + c] = tanhf(acc);
    }
  }
}

// standalone fps1 (fallback path: local must run LAST when scratch aliases d_out)
__global__ __launch_bounds__(512, 1) void fps1_kernel(const float* __restrict__ pts,
                                                      float* __restrict__ cen) {
  __shared__ __align__(16) char smem[16 * MM + 12 * SS1 + 128];
  fps_core<MM, SS1, 512>(pts + (size_t)blockIdx.x * MM * 3,
                         cen + (size_t)blockIdx.x * SS1 * 3, smem);
}

// standalone local MLP (fallback path), 8 pts per 512-thread block
__global__ __launch_bounds__(512) void local_mlp_kernel(
    const float* __restrict__ pos,
    const float* __restrict__ w0, const float* __restrict__ b0,
    const float* __restrict__ w1, const float* __restrict__ b1,
    const float* __restrict__ w2, const float* __restrict__ b2,
    float* __restrict__ out) {
  __shared__ float p[8][3];
  __shared__ float h0[8][64];
  __shared__ float h1[8][64];
  int t = threadIdx.x;
  size_t pid0 = (size_t)blockIdx.x * 8;
  if (t < 24) {
    int pp = t / 3, j = t % 3;
    p[pp][j] = pos[(pid0 + pp) * 3 + j];
  }
  __syncthreads();
  {
    int pp = t >> 6, c = t & 63;
    float acc = b0[c];
    #pragma unroll
    for (int j = 0; j < 3; ++j) acc += p[pp][j] * w0[j * 64 + c];
    h0[pp][c] = tanhf(acc);
  }
  __syncthreads();
  {
    int pp = t >> 6, c = t & 63;
    float acc = b1[c];
    #pragma unroll
    for (int j = 0; j < 64; ++j) acc += h0[pp][j] * w1[j * 64 + c];
    h1[pp][c] = tanhf(acc);
  }
  __syncthreads();
  #pragma unroll
  for (int r = 0; r < 2; ++r) {
    int o = t + 512 * r;
    int pp = o >> 7, c = o & 127;
    float acc = b2[c];
    #pragma unroll
    for (int j = 0; j < 64; ++j) acc += h1[pp][j] * w2[j * 128 + c];
    out[(pid0 + pp) * 128 + c] = tanhf(acc);
  }
}

// ======================================================================
// K_B: fps2 8-wave (blocks 0..3) U group1-with-embedded-nbr1 (blocks 4..1027).
// 131KB LDS -> 1 block/CU: fps2 gets EXCLUSIVE CUs. g1w1 (32KB) staged into
// LDS after the nbr phase (bw region dead then): layer2 weight reads become
// ds_read_b128 instead of ~300cy L2 round-trips (R15's -736us win).
// ======================================================================
__global__ __launch_bounds__(512) void k_fps2_g1(
    const float* __restrict__ pos, const float* __restrict__ x,
    const float* __restrict__ c1, float* __restrict__ c2,
    const float* __restrict__ g1w0, const float* __restrict__ g1b0,
    const float* __restrict__ g1w1, const float* __restrict__ g1b1,
    float* __restrict__ h1out) {
  __shared__ __align__(16) char smem[131264];
  int t = threadIdx.x;
  if (blockIdx.x < BB) {
    int b = blockIdx.x;
    fps_core<SS1, SS2, 512>(c1 + (size_t)b * SS1 * 3, c2 + (size_t)b * SS2 * 3, smem);
    return;
  }
  int g = blockIdx.x - BB;  // 0..1023, one 8-center task per block
  int lane = t & 63, wv = t >> 6;
  ull* bw = (ull*)smem + (size_t)wv * 1024;       // [8][1024] ull = 64KB
  int* nbs = (int*)(smem + 65536);                // [8][64] int
  float* cbl = (float*)(smem + 67584);            // [8][3]
  int tt = t & 255, half = t >> 8;
  {  // wave wv: neighbor query for center g*8+wv
    int cs = g * 8 + wv;
    int b = cs >> 11;
    const float* cp = c1 + (size_t)cs * 3;
    float cx = cp[0], cy = cp[1], cz = cp[2];
    int nout = nbr_wave<MM>(pos + (size_t)b * MM * 3, cx, cy, cz, 0.04f, bw);
    nbs[wv * 64 + lane] = nout;
    if (lane == 0) { cbl[wv * 3 + 0] = cx; cbl[wv * 3 + 1] = cy; cbl[wv * 3 + 2] = cz; }
  }
  __syncthreads();
  // stage g1w1 (64x128 f32 = 32KB) into the now-dead bw region
  {
    float4* wd = (float4*)smem;
    const float4* wsrc = (const float4*)g1w1;
    for (int i = t; i < 2048; i += 512) wd[i] = wsrc[i];
  }
  __syncthreads();
  const float* wlds = (const float*)smem;
  // dual-half group1: 4 rounds x 2 centers (R12/R13-verified math)
  for (int r = 0; r < 4; ++r) {
    int c_loc = 2 * r + half;
    int cs2 = g * 8 + c_loc;
    int bb = cs2 >> 11;
    float* feats = (float*)(smem + 67712 + half * 24576);  // [64][12]
    float* hbuf  = feats + 768;                            // [64][68]
    float* Mred  = hbuf + 4352;                            // [8][128]
    const int* nbp = nbs + c_loc * 64;
    const float* ccp = cbl + c_loc * 3;
    if (tt < 64) {
      int n = nbp[tt];
      int ni = ((unsigned)n < (unsigned)MM) ? n : 0;
      const float* pp = pos + ((size_t)bb * MM + ni) * 3;
      const float* xx = x + ((size_t)bb * MM + ni) * 3;
      float p0 = pp[0], p1 = pp[1], p2 = pp[2];
      float* fr = feats + tt * 12;
      fr[0] = p0; fr[1] = p1; fr[2] = p2;
      fr[3] = xx[0]; fr[4] = xx[1]; fr[5] = xx[2];
      fr[6] = p0 - ccp[0]; fr[7] = p1 - ccp[1]; fr[8] = p2 - ccp[2];
    }
    __syncthreads();
    {
      int k = tt >> 2, q4 = tt & 3;
      float acc[16];
      #pragma unroll
      for (int i = 0; i < 16; ++i) acc[i] = g1b0[q4 * 16 + i];
      #pragma unroll
      for (int j = 0; j < 9; ++j) {
        float f = feats[k * 12 + j];
        const float4* wr = (const float4*)(g1w0 + j * 64 + q4 * 16);
        #pragma unroll
        for (int i = 0; i < 4; ++i) {
          float4 wvv = wr[i];
          acc[4 * i + 0] += f * wvv.x;
          acc[4 * i + 1] += f * wvv.y;
          acc[4 * i + 2] += f * wvv.z;
          acc[4 * i + 3] += f * wvv.w;
        }
      }
      #pragma unroll
      for (int i = 0; i < 16; ++i) hbuf[k * 68 + q4 * 16 + i] = tanhf(acc[i]);
    }
    __syncthreads();
    {
      int kt = tt >> 5, ct = tt & 31;
      float acc[8][4];
      #pragma unroll
      for (int a = 0; a < 8; ++a)
        #pragma unroll
        for (int ci = 0; ci < 4; ++ci) acc[a][ci] = 0.f;
      const float* wbase = wlds + ct * 4;  // LDS-staged weights
      #pragma unroll 2
      for (int j = 0; j < 64; j += 2) {
        float2 fv[8];
        #pragma unroll
        for (int kk = 0; kk < 8; ++kk)
          fv[kk] = *(const float2*)&hbuf[(kt * 8 + kk) * 68 + j];
        float wja[4], wjb[4];
        *(float4*)&wja[0] = *(const float4*)(wbase + (size_t)j * 128);
        *(float4*)&wjb[0] = *(const float4*)(wbase + (size_t)(j + 1) * 128);
        #pragma unroll
        for (int kk = 0; kk < 8; ++kk)
          #pragma unroll
          for (int ci = 0; ci < 4; ++ci) {
            acc[kk][ci] += fv[kk].x * wja[ci];
            acc[kk][ci] += fv[kk].y * wjb[ci];
          }
      }
      float m[4];
      #pragma unroll
      for (int ci = 0; ci < 4; ++ci) m[ci] = -INFINITY;
      #pragma unroll
      for (int kk = 0; kk < 8; ++kk) {
        if (nbp[kt * 8 + kk] >= 0) {
          #pragma unroll
          for (int ci = 0; ci < 4; ++ci) m[ci] = fmaxf(m[ci], acc[kk][ci]);
        }
      }
      #pragma unroll
      for (int ci = 0; ci < 4; ++ci) Mred[kt * 128 + ct * 4 + ci] = m[ci];
    }
    __syncthreads();
    if (tt < 128) {
      float mxv = Mred[tt];
      #pragma unroll
      for (int r8 = 1; r8 < 8; ++r8) mxv = fmaxf(mxv, Mred[r8 * 128 + tt]);
      h1out[(size_t)cs2 * 128 + tt] = tanhf(mxv + g1b1[tt]);
    }
    __syncthreads();
  }
}

// ======================================================================
// K_C: group2-with-embedded-nbr2: 256 blocks x 8 centers.
// g2w0 rows 0..127 (64KB) staged into the dead bw region; layer2 unroll 4.
// ======================================================================
__global__ __launch_bounds__(512) void k_g2(
    const float* __restrict__ c1, const float* __restrict__ c2,
    const float* __restrict__ h1,
    const float* __restrict__ g2w0, const float* __restrict__ g2b0,
    const float* __restrict__ g2w1, const float* __restrict__ g2b1,
    float* __restrict__ h2out) {
  __shared__ __align__(16) char smem[151744];
  int t = threadIdx.x;
  int g = blockIdx.x;  // 0..255, one 8-center task per block
  int lane = t & 63, wv = t >> 6;
  ull* bw = (ull*)smem + (size_t)wv * 1024;
  int* nbs = (int*)(smem + 65536);
  float* cbl = (float*)(smem + 67584);
  int tt = t & 255, half = t >> 8;
  {
    int cs = g * 8 + wv;
    int b = cs >> 9;
    const float* cp = c2 + (size_t)cs * 3;
    float cx = cp[0], cy = cp[1], cz = cp[2];
    int nout = nbr_wave<SS1>(c1 + (size_t)b * SS1 * 3, cx, cy, cz, 0.16f, bw);
    nbs[wv * 64 + lane] = nout;
    if (lane == 0) { cbl[wv * 3 + 0] = cx; cbl[wv * 3 + 1] = cy; cbl[wv * 3 + 2] = cz; }
  }
  __syncthreads();
  // stage g2w0 rows 0..127 (128x128 f32 = 64KB) into the dead bw region
  {
    float4* wd = (float4*)smem;
    const float4* wsrc = (const float4*)g2w0;
    for (int i = t; i < 4096; i += 512) wd[i] = wsrc[i];
  }
  __syncthreads();
  const float* w0lds = (const float*)smem;
  for (int r = 0; r < 4; ++r) {
    int c_loc = 2 * r + half;
    int cs2 = g * 8 + c_loc;
    int bb = cs2 >> 9;
    float* fb   = (float*)(smem + 67712 + half * 41984);  // [64][132]
    float* Mred = fb + 64 * 132;                          // [8][256]
    const int* nbp = nbs + c_loc * 64;
    const float* ccp = cbl + c_loc * 3;
    {
      int k = tt >> 2, q4 = tt & 3;
      int n = nbp[k];
      int ni = ((unsigned)n < (unsigned)SS1) ? n : 0;
      const float* hrow = h1 + ((size_t)bb * SS1 + ni) * 128;
      #pragma unroll
      for (int i = 0; i < 32; ++i) fb[k * 132 + q4 * 32 + i] = hrow[q4 * 32 + i];
      if (q4 == 0) {
        const float* pr = c1 + ((size_t)bb * SS1 + ni) * 3;
        fb[k * 132 + 128] = pr[0] - ccp[0];
        fb[k * 132 + 129] = pr[1] - ccp[1];
        fb[k * 132 + 130] = pr[2] - ccp[2];
      }
    }
    __syncthreads();
    float acc1[32];
    {
      int k = tt >> 2, q4 = tt & 3;
      #pragma unroll
      for (int i = 0; i < 32; ++i) acc1[i] = g2b0[q4 * 32 + i];
      #pragma unroll 2
      for (int j = 0; j < 128; ++j) {  // rows 0..127 from LDS
        float f = fb[k * 132 + j];
        const float4* wr = (const float4*)(w0lds + (size_t)j * 128 + q4 * 32);
        #pragma unroll
        for (int i = 0; i < 8; ++i) {
          float4 wvv = wr[i];
          acc1[4 * i + 0] += f * wvv.x;
          acc1[4 * i + 1] += f * wvv.y;
          acc1[4 * i + 2] += f * wvv.z;
          acc1[4 * i + 3] += f * wvv.w;
        }
      }
      #pragma unroll
      for (int j = 128; j < 131; ++j) {  // last 3 rows from global
        float f = fb[k * 132 + j];
        const float4* wr = (const float4*)(g2w0 + (size_t)j * 128 + q4 * 32);
        #pragma unroll
        for (int i = 0; i < 8; ++i) {
          float4 wvv = wr[i];
          acc1[4 * i + 0] += f * wvv.x;
          acc1[4 * i + 1] += f * wvv.y;
          acc1[4 * i + 2] += f * wvv.z;
          acc1[4 * i + 3] += f * wvv.w;
        }
      }
    }
    __syncthreads();
    {
      int k = tt >> 2, q4 = tt & 3;
      #pragma unroll
      for (int i = 0; i < 32; ++i) fb[k * 132 + q4 * 32 + i] = tanhf(acc1[i]);
    }
    __syncthreads();
    {
      int kt = tt >> 5, ct = tt & 31;
      float acc[8][8];
      #pragma unroll
      for (int a = 0; a < 8; ++a)
        #pragma unroll
        for (int ci = 0; ci < 8; ++ci) acc[a][ci] = 0.f;
      const float* wbase = g2w1 + ct * 8;
      #pragma unroll 4
      for (int j = 0; j < 128; j += 2) {
        float2 fv[8];
        #pragma unroll
        for (int kk = 0; kk < 8; ++kk)
          fv[kk] = *(const float2*)&fb[(kt * 8 + kk) * 132 + j];
        float wja[8], wjb[8];
        const float4* wp0 = (const float4*)(wbase + (size_t)j * 256);
        const float4* wp1 = (const float4*)(wbase + (size_t)(j + 1) * 256);
        *(float4*)&wja[0] = wp0[0];
        *(float4*)&wja[4] = wp0[1];
        *(float4*)&wjb[0] = wp1[0];
        *(float4*)&wjb[4] = wp1[1];
        #pragma unroll
        for (int kk = 0; kk < 8; ++kk)
          #pragma unroll
          for (int ci = 0; ci < 8; ++ci) {
            acc[kk][ci] += fv[kk].x * wja[ci];
            acc[kk][ci] += fv[kk].y * wjb[ci];
          }
      }
      float m[8];
      #pragma unroll
      for (int ci = 0; ci < 8; ++ci) m[ci] = -INFINITY;
      #pragma unroll
      for (int kk = 0; kk < 8; ++kk) {
        if (nbp[kt * 8 + kk] >= 0) {
          #pragma unroll
          for (int ci = 0; ci < 8; ++ci) m[ci] = fmaxf(m[ci], acc[kk][ci]);
        }
      }
      #pragma unroll
      for (int ci = 0; ci < 8; ++ci) Mred[kt * 256 + ct * 8 + ci] = m[ci];
    }
    __syncthreads();
    {
      float mxv = Mred[tt];
      #pragma unroll
      for (int r8 = 1; r8 < 8; ++r8) mxv = fmaxf(mxv, Mred[r8 * 256 + tt]);
      h2out[(size_t)cs2 * 256 + tt] = tanhf(mxv + g2b1[tt]);
    }
    __syncthreads();
  }
}

// ---------------- global max over centers ----------------
__global__ __launch_bounds__(256) void gmax_kernel(const float* __restrict__ h2,
                                                   float* __restrict__ out) {
  int b = blockIdx.x, c = threadIdx.x;
  float mx = -INFINITY;
  for (int s = 0; s < SS2; ++s)
    mx = fmaxf(mx, h2[((size_t)b * SS2 + s) * 256 + c]);
  out[(size_t)BB * MM * 128 + b * 256 + c] = mx;
}

extern "C" void kernel_launch(void* const* d_in, const int* in_sizes, int n_in,
                              void* d_out, int out_size, void* d_ws, size_t ws_size,
                              hipStream_t stream) {
  const float* x    = (const float*)d_in[0];
  const float* pos  = (const float*)d_in[1];
  const float* lw0  = (const float*)d_in[2];
  const float* lb0  = (const float*)d_in[3];
  const float* lw1  = (const float*)d_in[4];
  const float* lb1  = (const float*)d_in[5];
  const float* lw2  = (const float*)d_in[6];
  const float* lb2  = (const float*)d_in[7];
  const float* g1w0 = (const float*)d_in[8];
  const float* g1b0 = (const float*)d_in[9];
  const float* g1w1 = (const float*)d_in[10];
  const float* g1b1 = (const float*)d_in[11];
  const float* g2w0 = (const float*)d_in[12];
  const float* g2b0 = (const float*)d_in[13];
  const float* g2w1 = (const float*)d_in[14];
  const float* g2b1 = (const float*)d_in[15];
  float* out = (float*)d_out;

  // Scratch (6.41 MB: nbr arrays eliminated -- embedded in group kernels).
  // Prefer d_ws; fall back to the local-output region of d_out (16.8 MB):
  // then local_mlp must run LAST and fps1 standalone FIRST.
  const size_t NEED = 6414336;
  bool has_ws = (ws_size >= NEED);
  char* sc = has_ws ? (char*)d_ws : (char*)d_out;
  float* h1 = (float*)(sc + 0);        // 4*2048*128 f32 = 4,194,304 B
  float* h2 = (float*)(sc + 4194304);  // 4*512*256 f32  = 2,097,152 B
  float* c1 = (float*)(sc + 6291456);  // 4*2048*3 f32   =    98,304 B
  float* c2 = (float*)(sc + 6389760);  // 4*512*3 f32    =    24,576 B

  if (has_ws) {
    k_fps1_local<<<BB + BB * MM / 8, 512, 0, stream>>>(
        pos, c1, lw0, lb0, lw1, lb1, lw2, lb2, out);
  } else {
    fps1_kernel<<<BB, 512, 0, stream>>>(pos, c1);
  }
  k_fps2_g1<<<BB + BB * SS1 / 8, 512, 0, stream>>>(
      pos, x, c1, c2, g1w0, g1b0, g1w1, g1b1, h1);
  k_g2<<<BB * SS2 / 8, 512, 0, stream>>>(
      c1, c2, h1, g2w0, g2b0, g2w1, g2b1, h2);
  gmax_kernel<<<BB, 256, 0, stream>>>(h2, out);
  if (!has_ws) {
    local_mlp_kernel<<<BB * MM / 8, 512, 0, stream>>>(pos, lw0, lb0, lw1, lb1, lw2, lb2, out);
  }
}